// Round 11
// baseline (171.693 us; speedup 1.0000x reference)
//
#include <hip/hip_runtime.h>

#define DM 1024
#define NHEADS 16
#define DHEAD 64
#define BB 2
#define SS 2048
#define BH (BB*NHEADS)

typedef __attribute__((ext_vector_type(8))) short short8;
typedef __attribute__((ext_vector_type(4))) float float4v;
typedef unsigned short ushort_t;

#define LN1E4_D32 0.28782313662425572f   // ln(10000)/32
#define SM_SCALE  0.18033688011112042f   // 0.125 * log2(e): QK softmax scale folded into Q

static __device__ __forceinline__ unsigned short f2bf(float f) {
    union { float f; unsigned u; } v; v.f = f;
    unsigned r = v.u + 0x7fffu + ((v.u >> 16) & 1u);
    return (unsigned short)(r >> 16);
}
static __device__ __forceinline__ float bf2f(unsigned short u) {
    union { float f; unsigned u; } v; v.u = ((unsigned)u) << 16;
    return v.f;
}
// packed f32x2 -> bf16x2 (RNE, bit-identical to f2bf)
static __device__ __forceinline__ unsigned cvtpk_bf16(float lo, float hi) {
    unsigned r;
    asm("v_cvt_pk_bf16_f32 %0, %1, %2" : "=v"(r) : "v"(lo), "v"(hi));
    return r;
}
// raw v_exp_f32: 2^x, no argument-scaling mul (scale pre-folded into Q)
static __device__ __forceinline__ float ex2(float x) {
    float r;
    asm("v_exp_f32 %0, %1" : "=v"(r) : "v"(x));
    return r;
}

// async global->LDS 16B copy: lds dest is wave-uniform base + lane*16
static __device__ __forceinline__ void gload16(const ushort_t* g, ushort_t* l) {
    __builtin_amdgcn_global_load_lds(
        (const __attribute__((address_space(1))) void*)g,
        (__attribute__((address_space(3))) void*)l, 16, 0, 0);
}

// ---------------- fused prepass: GEMM tiles (x,wq,wv,wo) + RoPE-K outputs ----------------
// blocks [0,3584): f32 -> bf16 pre-swizzled 128x32 GEMM tiles
// blocks [3584,4608): roped K (f32 out + bf16 swizzled attn tiles) + un-roped y GEMM tiles
__global__ __launch_bounds__(256) void prep_kernel(
        const float* __restrict__ x, const float* __restrict__ y,
        const float* __restrict__ wq, const float* __restrict__ wv,
        const float* __restrict__ wo,
        ushort_t* __restrict__ xb, ushort_t* __restrict__ wqb,
        ushort_t* __restrict__ wvb, ushort_t* __restrict__ wob,
        float* __restrict__ kout, ushort_t* __restrict__ khb,
        ushort_t* __restrict__ yb) {
    if (blockIdx.x < 3584) {
        int C = blockIdx.x * 256 + threadIdx.x;
        int c  = C & 511;
        int tl = C >> 9;
        int rb = tl >> 5, kb = tl & 31;
        const float* src; ushort_t* dst; int r0;
        if (rb < 32)      { src = x;  r0 = rb * 128;        dst = xb  + (size_t)tl * 4096; }
        else if (rb < 40) { src = wq; r0 = (rb - 32) * 128; dst = wqb + (size_t)(((rb - 32) * 32) + kb) * 4096; }
        else if (rb < 48) { src = wv; r0 = (rb - 40) * 128; dst = wvb + (size_t)(((rb - 40) * 32) + kb) * 4096; }
        else              { src = wo; r0 = (rb - 48) * 128; dst = wob + (size_t)(((rb - 48) * 32) + kb) * 4096; }
        int row = c >> 2, g = c & 3;
        int kk3 = g ^ ((row >> 1) & 3);
        const float* s = src + (size_t)(r0 + row) * DM + kb * 32 + kk3 * 8;
        float4 a0 = *reinterpret_cast<const float4*>(s);
        float4 a1 = *reinterpret_cast<const float4*>(s + 4);
        short8 v;
        v[0] = (short)f2bf(a0.x); v[1] = (short)f2bf(a0.y);
        v[2] = (short)f2bf(a0.z); v[3] = (short)f2bf(a0.w);
        v[4] = (short)f2bf(a1.x); v[5] = (short)f2bf(a1.y);
        v[6] = (short)f2bf(a1.z); v[7] = (short)f2bf(a1.w);
        *reinterpret_cast<short8*>(dst + c * 8) = v;
        return;
    }
    int t = (blockIdx.x - 3584) * 256 + threadIdx.x;
    int i8 = t & 3;
    int s  = (t >> 2) & (SS - 1);
    int bh = t >> 13;
    int h = bh & (NHEADS - 1), b = bh >> 4;

    const float* yp = y + ((size_t)(b * SS + s)) * DM + h * DHEAD + i8 * 8;
    float4 a0 = *reinterpret_cast<const float4*>(yp);
    float4 a1 = *reinterpret_cast<const float4*>(yp + 4);
    float4 b0 = *reinterpret_cast<const float4*>(yp + 32);
    float4 b1 = *reinterpret_cast<const float4*>(yp + 36);
    float u0[8] = {a0.x, a0.y, a0.z, a0.w, a1.x, a1.y, a1.z, a1.w};
    float u1[8] = {b0.x, b0.y, b0.z, b0.w, b1.x, b1.y, b1.z, b1.w};
    float lo[8], hi[8];
#pragma unroll
    for (int j = 0; j < 8; j++) {
        int i = i8 * 8 + j;
        float freq = __expf(-(float)i * LN1E4_D32);
        float th = (float)s * freq;
        float cv, sv;
        __sincosf(th, &sv, &cv);   // fast HW trig: rel err ~1e-6, invisible vs bf16/absmax
        lo[j] = u0[j] * cv - u1[j] * sv;
        hi[j] = u1[j] * cv + u0[j] * sv;
    }
    float* op = kout + ((size_t)bh * SS + s) * DHEAD + i8 * 8;
    *reinterpret_cast<float4*>(op)      = (float4){lo[0], lo[1], lo[2], lo[3]};
    *reinterpret_cast<float4*>(op + 4)  = (float4){lo[4], lo[5], lo[6], lo[7]};
    *reinterpret_cast<float4*>(op + 32) = (float4){hi[0], hi[1], hi[2], hi[3]};
    *reinterpret_cast<float4*>(op + 36) = (float4){hi[4], hi[5], hi[6], hi[7]};

    // roped bf16 swizzled attn K tiles
    ushort_t* kb = khb + ((size_t)bh * 32 + (s >> 6)) * 4096 + (s & 63) * 64;
    short8 vlo, vhi;
#pragma unroll
    for (int j = 0; j < 8; j++) { vlo[j] = (short)f2bf(lo[j]); vhi[j] = (short)f2bf(hi[j]); }
    *reinterpret_cast<short8*>(kb + ((i8 ^ (s & 7)) << 3))       = vlo;
    *reinterpret_cast<short8*>(kb + (((i8 + 4) ^ (s & 7)) << 3)) = vhi;

    // un-roped bf16 y GEMM tiles (same swizzle as the GEMM-tile branch)
    int rowm = b * SS + s;
    int rowin = rowm & 127, rbm = rowm >> 7;
    int g = i8 ^ ((rowin >> 1) & 3);
    ushort_t* yt = yb + ((size_t)(rbm * 32 + h * 2)) * 4096 + rowin * 32 + (g << 3);
    short8 ulo, uhi;
#pragma unroll
    for (int j = 0; j < 8; j++) { ulo[j] = (short)f2bf(u0[j]); uhi[j] = (short)f2bf(u1[j]); }
    *reinterpret_cast<short8*>(yt)        = ulo;   // kb = h*2
    *reinterpret_cast<short8*>(yt + 4096) = uhi;   // kb = h*2+1
}

// ---------------- 3 projection GEMMs: bf16 tiled inputs, global_load_lds double-buffer ----
// z=0 epilogue folds SM_SCALE (0.125*log2e) into the RoPE rotation: attn then uses raw
// v_exp_f32 (2^x) with no per-element scale mul.
__global__ __launch_bounds__(256, 2) void gemm3_kernel(
        const ushort_t* __restrict__ xb, const ushort_t* __restrict__ yb,
        const ushort_t* __restrict__ wqb, const ushort_t* __restrict__ wvb,
        const ushort_t* __restrict__ wob,
        ushort_t* __restrict__ qh, ushort_t* __restrict__ vt, ushort_t* __restrict__ v1h) {
    __shared__ __align__(16) char smem[34816];
    ushort_t* As = (ushort_t*)smem;              // [2][4096] double buffer
    ushort_t* Bs = (ushort_t*)(smem + 16384);    // [2][4096]
    ushort_t (*Ct)[136] = (ushort_t(*)[136])smem;   // epilogue reuse

    int bid = blockIdx.x;
    int xcd = bid & 7;
    int s_  = bid >> 3;
    int zo  = s_ >> 5;
    int z   = (zo == 0) ? 0 : (zo == 1 ? 2 : 1);
    int t_  = s_ & 31;
    int n0  = (t_ >> 2) * 128;
    int m0  = (xcd * 4 + (t_ & 3)) * 128;

    const ushort_t* A = (z == 1) ? yb : xb;
    const ushort_t* W = (z == 0) ? wqb : (z == 1 ? wvb : wob);
    ushort_t* O = (z == 0) ? qh : (z == 1 ? vt : v1h);

    const ushort_t* Atl = A + (size_t)(m0 >> 7) * 32 * 4096;
    const ushort_t* Wtl = W + (size_t)(n0 >> 7) * 32 * 4096;

    int tid = threadIdx.x;
    int wave = tid >> 6, lane = tid & 63, quad = lane >> 4, l15 = lane & 15;
    int wr = (wave >> 1) * 64, wc = (wave & 1) * 64;

    int gi0 = tid * 8, gi1 = (256 + tid) * 8;
    int li0 = (tid & 192) * 8, li1 = (256 + (tid & 192)) * 8;

    int aoff[4], boff[4];
#pragma unroll
    for (int mi = 0; mi < 4; mi++) {
        int row = wr + mi * 16 + l15;
        aoff[mi] = row * 32 + ((quad ^ ((row >> 1) & 3)) << 3);
    }
#pragma unroll
    for (int ni = 0; ni < 4; ni++) {
        int row = wc + ni * 16 + l15;
        boff[ni] = row * 32 + ((quad ^ ((row >> 1) & 3)) << 3);
    }

    float4v acc[4][4];
#pragma unroll
    for (int a = 0; a < 4; a++)
#pragma unroll
        for (int b = 0; b < 4; b++)
            acc[a][b] = (float4v){0.f, 0.f, 0.f, 0.f};

    gload16(Atl + gi0, As + li0); gload16(Atl + gi1, As + li1);
    gload16(Wtl + gi0, Bs + li0); gload16(Wtl + gi1, Bs + li1);
    int cur = 0;

    for (int kb = 0; kb < 32; kb++) {
        __syncthreads();
        if (kb + 1 < 32) {
            const ushort_t* at = Atl + (size_t)(kb + 1) * 4096;
            const ushort_t* wt = Wtl + (size_t)(kb + 1) * 4096;
            int nb = (cur ^ 1) * 4096;
            gload16(at + gi0, As + nb + li0); gload16(at + gi1, As + nb + li1);
            gload16(wt + gi0, Bs + nb + li0); gload16(wt + gi1, Bs + nb + li1);
        }
        const ushort_t* Ac = As + cur * 4096;
        const ushort_t* Bc = Bs + cur * 4096;
        short8 af[4], bfr[4];
#pragma unroll
        for (int mi = 0; mi < 4; mi++)
            af[mi] = *reinterpret_cast<const short8*>(&Ac[aoff[mi]]);
#pragma unroll
        for (int ni = 0; ni < 4; ni++)
            bfr[ni] = *reinterpret_cast<const short8*>(&Bc[boff[ni]]);
#pragma unroll
        for (int mi = 0; mi < 4; mi++)
#pragma unroll
            for (int ni = 0; ni < 4; ni++)
                acc[mi][ni] = __builtin_amdgcn_mfma_f32_16x16x32_bf16(af[mi], bfr[ni], acc[mi][ni], 0, 0, 0);
        cur ^= 1;
    }

    if (z == 0) {
#pragma unroll
        for (int mi = 0; mi < 4; mi++)
#pragma unroll
            for (int r = 0; r < 4; r++) {
                int m = m0 + wr + mi * 16 + quad * 4 + r;
                float pos = (float)(m & (SS - 1));
#pragma unroll
                for (int ni = 0; ni < 2; ni++) {
                    int d = ni * 16 + l15;
                    float f = __expf(-(float)d * LN1E4_D32);
                    float th = pos * f;
                    float cv, sv;
                    __sincosf(th, &sv, &cv);
                    cv *= SM_SCALE; sv *= SM_SCALE;   // fold softmax scale into Q
                    float u0 = acc[mi][ni][r], u1 = acc[mi][ni + 2][r];
                    acc[mi][ni][r]     = u0 * cv - u1 * sv;
                    acc[mi][ni + 2][r] = u1 * cv + u0 * sv;
                }
            }
    }

    __syncthreads();
#pragma unroll
    for (int mi = 0; mi < 4; mi++)
#pragma unroll
        for (int ni = 0; ni < 4; ni++) {
            int col = wc + ni * 16 + l15;
#pragma unroll
            for (int r = 0; r < 4; r++)
                Ct[wr + mi * 16 + quad * 4 + r][col] = f2bf(acc[mi][ni][r]);
        }
    __syncthreads();
    int h0 = n0 >> 6;
    if (z == 1) {
        int b = m0 >> 11;
        int s0 = m0 & (SS - 1);
#pragma unroll
        for (int it = 0; it < 8; it++) {
            int c = it * 256 + tid;
            int dh  = c & 63;
            int k16 = (c >> 6) & 15;
            int hh  = c >> 10;
            short8 v;
#pragma unroll
            for (int e = 0; e < 8; e++)
                v[e] = (short)Ct[k16 * 8 + e][hh * 64 + dh];
            int kt = (s0 >> 6) + (k16 >> 3);
            size_t off = ((size_t)((b * NHEADS + h0 + hh) * 32 + kt)) * 4096
                       + dh * 64 + (((k16 & 7) ^ (dh & 7)) << 3);
            *reinterpret_cast<short8*>(&O[off]) = v;
        }
    } else {
#pragma unroll
        for (int it = 0; it < 8; it++) {
            int c = it * 256 + tid;
            int o = c >> 3, j = c & 7;
            int hh = o >> 7, mr = o & 127;
            int m = m0 + mr, b = m >> 11, si = m & (SS - 1);
            uint4 v = *reinterpret_cast<const uint4*>(&Ct[mr][hh * 64 + j * 8]);
            *reinterpret_cast<uint4*>(
                &O[((size_t)((b * NHEADS + h0 + hh) * SS + si)) * DHEAD + j * 8]) = v;
        }
    }
}

// ---------------- flash attention: causal-paired blocks, 16 waves, tile-parity split.
// Waves 0-7 compute EVEN tiles, waves 8-15 the SAME queries' ODD tiles -> each wave runs
// ONE tile chain per barrier period with its OWN Ps buffer (no aliasing, true ILP), half
// the chains per wave. Partial O/sum combined through dead K/V LDS at the end.
// FIX vs r10: __syncthreads() between main loop and the combine deposit — cbuf aliases
// the K/V ring, so the ring must be block-wide dead before any wave writes partials.
template<bool MASKED>
static __device__ __forceinline__ void attn_tile(
        const ushort_t* __restrict__ Kc, const ushort_t* __restrict__ Vc, int kbase,
        int quad, int l15, int q0w, const short8* qf, const short8& onesf,
        ushort_t* __restrict__ Psw, float4v* Oa, float4v& sum4) {
    float4v sa[4];
#pragma unroll
    for (int t2 = 0; t2 < 4; t2++) sa[t2] = (float4v){0.f, 0.f, 0.f, 0.f};
    __builtin_amdgcn_s_setprio(1);
#pragma unroll
    for (int t2 = 0; t2 < 4; t2++) {
        int key = t2 * 16 + l15;
        int ro = key * 64, sw = key & 7;
#pragma unroll
        for (int half = 0; half < 2; half++) {
            short8 kf = *reinterpret_cast<const short8*>(&Kc[ro + (((half * 4 + quad) ^ sw) << 3)]);
            sa[t2] = __builtin_amdgcn_mfma_f32_16x16x32_bf16(kf, qf[half], sa[t2], 0, 0, 0);
        }
    }
    __builtin_amdgcn_s_setprio(0);
    int query = q0w + l15;
    int swl = l15 & 7;
#pragma unroll
    for (int t2 = 0; t2 < 4; t2++) {
        float p[4];
#pragma unroll
        for (int r = 0; r < 4; r++) {
            float e = ex2(sa[t2][r]);          // 2^(scaled score): scale folded into Q
            if (MASKED) {
                int key = kbase + t2 * 16 + quad * 4 + r;
                p[r] = (key <= query) ? e : 0.f;
            } else {
                p[r] = e;
            }
        }
        unsigned w0 = cvtpk_bf16(p[0], p[1]);
        unsigned w1 = cvtpk_bf16(p[2], p[3]);
        int chunk = (((t2 * 2 + (quad >> 1)) ^ swl) << 3) + (quad & 1) * 4;
        *reinterpret_cast<unsigned*>(&Psw[l15 * 64 + chunk])     = w0;
        *reinterpret_cast<unsigned*>(&Psw[l15 * 64 + chunk + 2]) = w1;
    }
    // per-wave LDS: compiler-inserted lgkmcnt orders writes before these reads
    short8 pf0 = *reinterpret_cast<const short8*>(&Psw[l15 * 64 + ((quad ^ swl) << 3)]);
    short8 pf1 = *reinterpret_cast<const short8*>(&Psw[l15 * 64 + (((4 + quad) ^ swl) << 3)]);
    __builtin_amdgcn_s_setprio(1);
#pragma unroll
    for (int t = 0; t < 4; t++) {
        int dh = t * 16 + l15;
        int ro = dh * 64, sw = dh & 7;
        short8 vf0 = *reinterpret_cast<const short8*>(&Vc[ro + ((quad ^ sw) << 3)]);
        short8 vf1 = *reinterpret_cast<const short8*>(&Vc[ro + (((4 + quad) ^ sw) << 3)]);
        Oa[t] = __builtin_amdgcn_mfma_f32_16x16x32_bf16(pf0, vf0, Oa[t], 0, 0, 0);
        Oa[t] = __builtin_amdgcn_mfma_f32_16x16x32_bf16(pf1, vf1, Oa[t], 0, 0, 0);
    }
    // softmax denominator on the matrix pipe: sum4[r] = sum_k P[query(quad*4+r)][k]
    sum4 = __builtin_amdgcn_mfma_f32_16x16x32_bf16(pf0, onesf, sum4, 0, 0, 0);
    sum4 = __builtin_amdgcn_mfma_f32_16x16x32_bf16(pf1, onesf, sum4, 0, 0, 0);
    __builtin_amdgcn_s_setprio(0);
}

__global__ __launch_bounds__(1024, 4) void attn_kernel(
        const ushort_t* __restrict__ qh, const float* __restrict__ kf32,
        const ushort_t* __restrict__ khb, const ushort_t* __restrict__ vtb,
        const ushort_t* __restrict__ v1h, float* __restrict__ out) {
    __shared__ __align__(16) ushort_t KV[8][4096];   // [0..3]=K ring, [4..7]=V ring; 64KB
    __shared__ __align__(16) ushort_t Ps[16][1024];  // per-wave swizzled P; 96KB LDS total

    // 512 blocks: 16 pairs x 32 bh; longest pair (p=0) first, 4 heads per XCD
    int bid = blockIdx.x;
    int bh = (bid & 7) * 4 + ((bid >> 3) & 3);
    int p  = bid >> 5;                    // 0..15

    int tid = threadIdx.x, wave = tid >> 6, lane = tid & 63, quad = lane >> 4, l15 = lane & 15;
    int par   = wave >> 3;                // tile parity this wave computes
    int qslot = wave & 7;                 // query slot (shared by parity partners)
    int jq  = (qslot < 4) ? p : (31 - p); // this slot's 64-query block
    int q0w = jq * 64 + (qslot & 3) * 16;
    const ushort_t* qp  = qh  + (size_t)bh * SS * DHEAD;
    const float*    kp  = kf32 + (size_t)bh * SS * DHEAD;
    const ushort_t* v1p = v1h + (size_t)bh * SS * DHEAD;
    const ushort_t* ktb = khb + (size_t)bh * 32 * 4096;
    const ushort_t* vtt = vtb + (size_t)bh * 32 * 4096;

    short8 qf[2];
    qf[0] = *reinterpret_cast<const short8*>(&qp[(q0w + l15) * DHEAD + quad * 8]);
    qf[1] = *reinterpret_cast<const short8*>(&qp[(q0w + l15) * DHEAD + 32 + quad * 8]);
    short8 onesf;
#pragma unroll
    for (int j = 0; j < 8; j++) onesf[j] = (short)0x3F80;   // bf16 1.0

    float4v Oa[4];
#pragma unroll
    for (int t = 0; t < 4; t++) Oa[t] = (float4v){0.f, 0.f, 0.f, 0.f};
    float4v sum4 = (float4v){0.f, 0.f, 0.f, 0.f};

    int hid  = tid & 511;        // position within staging half
    int shalf = tid >> 9;        // 0/1: this half stages tile kt2+2+shalf
    int gi = hid * 8;            // 512 threads x 16B = one full 8KB tile
    int li = (hid & 448) * 8;    // wave-uniform LDS base

    int ntiles = 32 - p;         // >= 17; HI slot's range covers LO's
    // prologue: half 0 stages tile 0, half 1 stages tile 1
    {
        const ushort_t* gk = ktb + (size_t)shalf * 4096;
        const ushort_t* gv = vtt + (size_t)shalf * 4096;
        gload16(gk + gi, &KV[shalf][li]);
        gload16(gv + gi, &KV[4 + shalf][li]);
    }

    for (int kt2 = 0; kt2 < ntiles; kt2 += 2) {
        __syncthreads();   // drains vmcnt -> slots kt2&3,(kt2+1)&3 ready; old reads done
        int pf = kt2 + 2 + shalf;
        if (pf < ntiles) {
            const ushort_t* gk = ktb + (size_t)pf * 4096;
            const ushort_t* gv = vtt + (size_t)pf * 4096;
            int nb = pf & 3;
            gload16(gk + gi, &KV[nb][li]);
            gload16(gv + gi, &KV[4 + nb][li]);
        }
        int kt = kt2 + par;          // this wave's parity tile
        if (kt < ntiles) {
            int kbase = kt * 64, sl = kt & 3;
            if (kbase <= q0w + 15) {            // wave-uniform causal skip
                if (kbase + 63 <= q0w)
                    attn_tile<false>(KV[sl], KV[4 + sl], kbase, quad, l15, q0w, qf, onesf,
                                     &Ps[wave][0], Oa, sum4);
                else
                    attn_tile<true>(KV[sl], KV[4 + sl], kbase, quad, l15, q0w, qf, onesf,
                                    &Ps[wave][0], Oa, sum4);
            }
        }
    }

    __syncthreads();   // K/V ring must be block-wide dead before cbuf aliases it (r10 fix)

    // combine parity partners: odd waves deposit Oa+sum4 into dead K/V LDS (stride 21
    // floats -> conflict-free), even waves add. 8 waves x 64 lanes x 21 f32 = 42KB < 64KB.
    float* cbuf = reinterpret_cast<float*>(&KV[0][0]);
    if (par == 1) {
        float* dst = cbuf + (qslot * 64 + lane) * 21;
#pragma unroll
        for (int t = 0; t < 4; t++)
#pragma unroll
            for (int r = 0; r < 4; r++) dst[t * 4 + r] = Oa[t][r];
#pragma unroll
        for (int r = 0; r < 4; r++) dst[16 + r] = sum4[r];
    }
    __syncthreads();
    if (par == 0) {
        const float* src = cbuf + (qslot * 64 + lane) * 21;
#pragma unroll
        for (int t = 0; t < 4; t++)
#pragma unroll
            for (int r = 0; r < 4; r++) Oa[t][r] += src[t * 4 + r];
#pragma unroll
        for (int r = 0; r < 4; r++) sum4[r] += src[16 + r];

        // Ps[wave] is dead: alias per-wave sdiag (16 f32) onto it
        float* sdiag = reinterpret_cast<float*>(&Ps[wave][32]);

        // diagonal extra key: s_d = qs[i] . rope(k_roped[i]) (log2 domain), value v1[i]
        int sk = q0w + l15;
        const float* krow = kp + (size_t)sk * DHEAD;
        short8 k1lo, k1hi;
#pragma unroll
        for (int j = 0; j < 8; j++) {
            int d = quad * 8 + j;
            float f = __expf(-(float)d * LN1E4_D32);
            float th = (float)sk * f;
            float cv, sv;
            __sincosf(th, &sv, &cv);
            float a = krow[d], b2 = krow[d + 32];
            k1lo[j] = (short)f2bf(a * cv - b2 * sv);
            k1hi[j] = (short)f2bf(b2 * cv + a * sv);
        }
        float4v sd4 = (float4v){0.f, 0.f, 0.f, 0.f};
        sd4 = __builtin_amdgcn_mfma_f32_16x16x32_bf16(qf[0], k1lo, sd4, 0, 0, 0);
        sd4 = __builtin_amdgcn_mfma_f32_16x16x32_bf16(qf[1], k1hi, sd4, 0, 0, 0);
#pragma unroll
        for (int r = 0; r < 4; r++)
            if (l15 == quad * 4 + r) sdiag[l15] = sd4[r];
        // per-wave LDS write->read ordered by lgkmcnt within the wave; no barrier needed

        int b = bh >> 4, h = bh & (NHEADS - 1);
#pragma unroll
        for (int r = 0; r < 4; r++) {
            float pd = ex2(sdiag[quad * 4 + r]);
            int query = q0w + quad * 4 + r;
            float linv = 1.f / (sum4[r] + pd);
#pragma unroll
            for (int t = 0; t < 4; t++) {
                float v1v = bf2f(v1p[query * DHEAD + t * 16 + l15]);
                float o = (Oa[t][r] + pd * v1v) * linv;
                out[(b * SS + query) * DM + h * DHEAD + t * 16 + l15] = o;
            }
        }
    }
}

extern "C" void kernel_launch(void* const* d_in, const int* in_sizes, int n_in,
                              void* d_out, int out_size, void* d_ws, size_t ws_size,
                              hipStream_t stream) {
    const float* x  = (const float*)d_in[0];
    const float* y  = (const float*)d_in[1];
    const float* wq = (const float*)d_in[2];
    // d_in[3] = wk is unused by the reference
    const float* wv = (const float*)d_in[4];
    const float* wo = (const float*)d_in[5];
    float* outp  = (float*)d_out;                       // output 0: (2,2048,1024) f32
    float* k_out = outp + (size_t)BB * SS * DM;         // output 1: roped K (2,16,2048,64) f32

    char* ws = (char*)d_ws;
    ushort_t* vtb = (ushort_t*)(ws);                  // 8 MB  V^T swizzled attn tiles
    ushort_t* v1b = (ushort_t*)(ws + (8ull  << 20));  // 8 MB  V1 heads-layout bf16
    ushort_t* qhb = (ushort_t*)(ws + (16ull << 20));  // 8 MB  Q heads-layout bf16 (pre-scaled)
    ushort_t* khb = (ushort_t*)(ws + (24ull << 20));  // 8 MB  roped-K swizzled attn tiles
    ushort_t* xb  = (ushort_t*)(ws + (32ull << 20));  // 8 MB  x bf16 GEMM tiles
    ushort_t* yb  = (ushort_t*)(ws + (40ull << 20));  // 8 MB  y bf16 GEMM tiles
    ushort_t* wqb = (ushort_t*)(ws + (48ull << 20));  // 2 MB
    ushort_t* wvb = (ushort_t*)(ws + (50ull << 20));  // 2 MB
    ushort_t* wob = (ushort_t*)(ws + (52ull << 20));  // 2 MB  (total 54 MB)

    prep_kernel<<<4608, 256, 0, stream>>>(x, y, wq, wv, wo, xb, wqb, wvb, wob,
                                          k_out, khb, yb);
    gemm3_kernel<<<768, 256, 0, stream>>>(xb, yb, wqb, wvb, wob, qhb, vtb, v1b);
    attn_kernel<<<512, 1024, 0, stream>>>(qhb, k_out, khb, vtb, v1b, outp);
}

// Round 12
// 164.216 us; speedup vs baseline: 1.0455x; 1.0455x over previous
//
#include <hip/hip_runtime.h>

#define DM 1024
#define NHEADS 16
#define DHEAD 64
#define BB 2
#define SS 2048
#define BH (BB*NHEADS)

typedef __attribute__((ext_vector_type(8))) short short8;
typedef __attribute__((ext_vector_type(4))) float float4v;
typedef unsigned short ushort_t;

#define LN1E4_D32 0.28782313662425572f   // ln(10000)/32
#define SM_SCALE  0.18033688011112042f   // 0.125 * log2(e): QK softmax scale folded into Q

static __device__ __forceinline__ unsigned short f2bf(float f) {
    union { float f; unsigned u; } v; v.f = f;
    unsigned r = v.u + 0x7fffu + ((v.u >> 16) & 1u);
    return (unsigned short)(r >> 16);
}
static __device__ __forceinline__ float bf2f(unsigned short u) {
    union { float f; unsigned u; } v; v.u = ((unsigned)u) << 16;
    return v.f;
}
// packed f32x2 -> bf16x2 (RNE, bit-identical to f2bf)
static __device__ __forceinline__ unsigned cvtpk_bf16(float lo, float hi) {
    unsigned r;
    asm("v_cvt_pk_bf16_f32 %0, %1, %2" : "=v"(r) : "v"(lo), "v"(hi));
    return r;
}
// raw v_exp_f32: 2^x, no argument-scaling mul (scale pre-folded into Q)
static __device__ __forceinline__ float ex2(float x) {
    float r;
    asm("v_exp_f32 %0, %1" : "=v"(r) : "v"(x));
    return r;
}

// async global->LDS 16B copy: lds dest is wave-uniform base + lane*16
static __device__ __forceinline__ void gload16(const ushort_t* g, ushort_t* l) {
    __builtin_amdgcn_global_load_lds(
        (const __attribute__((address_space(1))) void*)g,
        (__attribute__((address_space(3))) void*)l, 16, 0, 0);
}

// ---------------- fused prepass: GEMM tiles (x,wq,wv,wo) + RoPE-K outputs ----------------
// blocks [0,3584): f32 -> bf16 pre-swizzled 128x32 GEMM tiles
// blocks [3584,4608): roped K (f32 out + bf16 swizzled attn tiles) + un-roped y GEMM tiles
__global__ __launch_bounds__(256) void prep_kernel(
        const float* __restrict__ x, const float* __restrict__ y,
        const float* __restrict__ wq, const float* __restrict__ wv,
        const float* __restrict__ wo,
        ushort_t* __restrict__ xb, ushort_t* __restrict__ wqb,
        ushort_t* __restrict__ wvb, ushort_t* __restrict__ wob,
        float* __restrict__ kout, ushort_t* __restrict__ khb,
        ushort_t* __restrict__ yb) {
    if (blockIdx.x < 3584) {
        int C = blockIdx.x * 256 + threadIdx.x;
        int c  = C & 511;
        int tl = C >> 9;
        int rb = tl >> 5, kb = tl & 31;
        const float* src; ushort_t* dst; int r0;
        if (rb < 32)      { src = x;  r0 = rb * 128;        dst = xb  + (size_t)tl * 4096; }
        else if (rb < 40) { src = wq; r0 = (rb - 32) * 128; dst = wqb + (size_t)(((rb - 32) * 32) + kb) * 4096; }
        else if (rb < 48) { src = wv; r0 = (rb - 40) * 128; dst = wvb + (size_t)(((rb - 40) * 32) + kb) * 4096; }
        else              { src = wo; r0 = (rb - 48) * 128; dst = wob + (size_t)(((rb - 48) * 32) + kb) * 4096; }
        int row = c >> 2, g = c & 3;
        int kk3 = g ^ ((row >> 1) & 3);
        const float* s = src + (size_t)(r0 + row) * DM + kb * 32 + kk3 * 8;
        float4 a0 = *reinterpret_cast<const float4*>(s);
        float4 a1 = *reinterpret_cast<const float4*>(s + 4);
        short8 v;
        v[0] = (short)f2bf(a0.x); v[1] = (short)f2bf(a0.y);
        v[2] = (short)f2bf(a0.z); v[3] = (short)f2bf(a0.w);
        v[4] = (short)f2bf(a1.x); v[5] = (short)f2bf(a1.y);
        v[6] = (short)f2bf(a1.z); v[7] = (short)f2bf(a1.w);
        *reinterpret_cast<short8*>(dst + c * 8) = v;
        return;
    }
    int t = (blockIdx.x - 3584) * 256 + threadIdx.x;
    int i8 = t & 3;
    int s  = (t >> 2) & (SS - 1);
    int bh = t >> 13;
    int h = bh & (NHEADS - 1), b = bh >> 4;

    const float* yp = y + ((size_t)(b * SS + s)) * DM + h * DHEAD + i8 * 8;
    float4 a0 = *reinterpret_cast<const float4*>(yp);
    float4 a1 = *reinterpret_cast<const float4*>(yp + 4);
    float4 b0 = *reinterpret_cast<const float4*>(yp + 32);
    float4 b1 = *reinterpret_cast<const float4*>(yp + 36);
    float u0[8] = {a0.x, a0.y, a0.z, a0.w, a1.x, a1.y, a1.z, a1.w};
    float u1[8] = {b0.x, b0.y, b0.z, b0.w, b1.x, b1.y, b1.z, b1.w};
    float lo[8], hi[8];
#pragma unroll
    for (int j = 0; j < 8; j++) {
        int i = i8 * 8 + j;
        float freq = __expf(-(float)i * LN1E4_D32);
        float th = (float)s * freq;
        float cv, sv;
        __sincosf(th, &sv, &cv);   // fast HW trig: rel err ~1e-6, invisible vs bf16/absmax
        lo[j] = u0[j] * cv - u1[j] * sv;
        hi[j] = u1[j] * cv + u0[j] * sv;
    }
    float* op = kout + ((size_t)bh * SS + s) * DHEAD + i8 * 8;
    *reinterpret_cast<float4*>(op)      = (float4){lo[0], lo[1], lo[2], lo[3]};
    *reinterpret_cast<float4*>(op + 4)  = (float4){lo[4], lo[5], lo[6], lo[7]};
    *reinterpret_cast<float4*>(op + 32) = (float4){hi[0], hi[1], hi[2], hi[3]};
    *reinterpret_cast<float4*>(op + 36) = (float4){hi[4], hi[5], hi[6], hi[7]};

    // roped bf16 swizzled attn K tiles
    ushort_t* kb = khb + ((size_t)bh * 32 + (s >> 6)) * 4096 + (s & 63) * 64;
    short8 vlo, vhi;
#pragma unroll
    for (int j = 0; j < 8; j++) { vlo[j] = (short)f2bf(lo[j]); vhi[j] = (short)f2bf(hi[j]); }
    *reinterpret_cast<short8*>(kb + ((i8 ^ (s & 7)) << 3))       = vlo;
    *reinterpret_cast<short8*>(kb + (((i8 + 4) ^ (s & 7)) << 3)) = vhi;

    // un-roped bf16 y GEMM tiles (same swizzle as the GEMM-tile branch)
    int rowm = b * SS + s;
    int rowin = rowm & 127, rbm = rowm >> 7;
    int g = i8 ^ ((rowin >> 1) & 3);
    ushort_t* yt = yb + ((size_t)(rbm * 32 + h * 2)) * 4096 + rowin * 32 + (g << 3);
    short8 ulo, uhi;
#pragma unroll
    for (int j = 0; j < 8; j++) { ulo[j] = (short)f2bf(u0[j]); uhi[j] = (short)f2bf(u1[j]); }
    *reinterpret_cast<short8*>(yt)        = ulo;   // kb = h*2
    *reinterpret_cast<short8*>(yt + 4096) = uhi;   // kb = h*2+1
}

// ---------------- projection GEMMs, A-SHARING MERGE ----------------
// blocks [0,256): MERGED x-GEMMs — Q = rope(x*wq^T) AND V1 = x*wo^T share one A staging
// (A staged once, both B tiles staged; 32 MFMA per barrier, -33% barriers, -17% traffic).
// blocks [256,512): V = y*wv^T -> pre-transposed swizzled V^T tiles.
// Grid 512 = exactly 2 blocks/CU, all resident. Math order per output unchanged.
__global__ __launch_bounds__(256, 2) void gemm3_kernel(
        const ushort_t* __restrict__ xb, const ushort_t* __restrict__ yb,
        const ushort_t* __restrict__ wqb, const ushort_t* __restrict__ wvb,
        const ushort_t* __restrict__ wob,
        ushort_t* __restrict__ qh, ushort_t* __restrict__ vt, ushort_t* __restrict__ v1h) {
    __shared__ __align__(16) char smem[49152];
    ushort_t* As = (ushort_t*)smem;              // [2][4096] A double buffer
    ushort_t* Bs = (ushort_t*)(smem + 16384);    // [2][4096] B1 (wq or wv)
    ushort_t* Cs = (ushort_t*)(smem + 32768);    // [2][4096] B2 (wo; merged only)
    ushort_t (*Ct)[136] = (ushort_t(*)[136])smem;   // epilogue reuse

    int bid = blockIdx.x;
    int xcd = bid & 7;
    int s_  = bid >> 3;          // 0..63
    int merged = (s_ < 32);
    int t_  = s_ & 31;
    int n0  = (t_ >> 2) * 128;
    int m0  = (xcd * 4 + (t_ & 3)) * 128;

    const ushort_t* A  = merged ? xb : yb;
    const ushort_t* W1 = merged ? wqb : wvb;

    const ushort_t* Atl = A   + (size_t)(m0 >> 7) * 32 * 4096;
    const ushort_t* W1t = W1  + (size_t)(n0 >> 7) * 32 * 4096;
    const ushort_t* W2t = wob + (size_t)(n0 >> 7) * 32 * 4096;   // merged only

    int tid = threadIdx.x;
    int wave = tid >> 6, lane = tid & 63, quad = lane >> 4, l15 = lane & 15;
    int wr = (wave >> 1) * 64, wc = (wave & 1) * 64;

    int gi0 = tid * 8, gi1 = (256 + tid) * 8;
    int li0 = (tid & 192) * 8, li1 = (256 + (tid & 192)) * 8;

    int aoff[4], boff[4];
#pragma unroll
    for (int mi = 0; mi < 4; mi++) {
        int row = wr + mi * 16 + l15;
        aoff[mi] = row * 32 + ((quad ^ ((row >> 1) & 3)) << 3);
    }
#pragma unroll
    for (int ni = 0; ni < 4; ni++) {
        int row = wc + ni * 16 + l15;
        boff[ni] = row * 32 + ((quad ^ ((row >> 1) & 3)) << 3);
    }

    float4v acc1[4][4], acc2[4][4];
#pragma unroll
    for (int a = 0; a < 4; a++)
#pragma unroll
        for (int b = 0; b < 4; b++) {
            acc1[a][b] = (float4v){0.f, 0.f, 0.f, 0.f};
            acc2[a][b] = (float4v){0.f, 0.f, 0.f, 0.f};
        }

    gload16(Atl + gi0, As + li0); gload16(Atl + gi1, As + li1);
    gload16(W1t + gi0, Bs + li0); gload16(W1t + gi1, Bs + li1);
    if (merged) { gload16(W2t + gi0, Cs + li0); gload16(W2t + gi1, Cs + li1); }
    int cur = 0;

    for (int kb = 0; kb < 32; kb++) {
        __syncthreads();
        if (kb + 1 < 32) {
            const ushort_t* at = Atl + (size_t)(kb + 1) * 4096;
            const ushort_t* w1 = W1t + (size_t)(kb + 1) * 4096;
            int nb = (cur ^ 1) * 4096;
            gload16(at + gi0, As + nb + li0); gload16(at + gi1, As + nb + li1);
            gload16(w1 + gi0, Bs + nb + li0); gload16(w1 + gi1, Bs + nb + li1);
            if (merged) {
                const ushort_t* w2 = W2t + (size_t)(kb + 1) * 4096;
                gload16(w2 + gi0, Cs + nb + li0); gload16(w2 + gi1, Cs + nb + li1);
            }
        }
        const ushort_t* Ac = As + cur * 4096;
        const ushort_t* Bc = Bs + cur * 4096;
        const ushort_t* Cc = Cs + cur * 4096;
        short8 af[4], b1[4];
#pragma unroll
        for (int mi = 0; mi < 4; mi++)
            af[mi] = *reinterpret_cast<const short8*>(&Ac[aoff[mi]]);
#pragma unroll
        for (int ni = 0; ni < 4; ni++)
            b1[ni] = *reinterpret_cast<const short8*>(&Bc[boff[ni]]);
#pragma unroll
        for (int mi = 0; mi < 4; mi++)
#pragma unroll
            for (int ni = 0; ni < 4; ni++)
                acc1[mi][ni] = __builtin_amdgcn_mfma_f32_16x16x32_bf16(af[mi], b1[ni], acc1[mi][ni], 0, 0, 0);
        if (merged) {
            short8 b2[4];
#pragma unroll
            for (int ni = 0; ni < 4; ni++)
                b2[ni] = *reinterpret_cast<const short8*>(&Cc[boff[ni]]);
#pragma unroll
            for (int mi = 0; mi < 4; mi++)
#pragma unroll
                for (int ni = 0; ni < 4; ni++)
                    acc2[mi][ni] = __builtin_amdgcn_mfma_f32_16x16x32_bf16(af[mi], b2[ni], acc2[mi][ni], 0, 0, 0);
        }
        cur ^= 1;
    }

    int h0 = n0 >> 6;
    if (merged) {
        // RoPE (scale-folded) on acc1 = Q
#pragma unroll
        for (int mi = 0; mi < 4; mi++)
#pragma unroll
            for (int r = 0; r < 4; r++) {
                int m = m0 + wr + mi * 16 + quad * 4 + r;
                float pos = (float)(m & (SS - 1));
#pragma unroll
                for (int ni = 0; ni < 2; ni++) {
                    int d = ni * 16 + l15;
                    float f = __expf(-(float)d * LN1E4_D32);
                    float th = pos * f;
                    float cv, sv;
                    __sincosf(th, &sv, &cv);
                    cv *= SM_SCALE; sv *= SM_SCALE;   // fold softmax scale into Q
                    float u0 = acc1[mi][ni][r], u1 = acc1[mi][ni + 2][r];
                    acc1[mi][ni][r]     = u0 * cv - u1 * sv;
                    acc1[mi][ni + 2][r] = u1 * cv + u0 * sv;
                }
            }
        // pass 1: Q -> heads-layout qh
        __syncthreads();
#pragma unroll
        for (int mi = 0; mi < 4; mi++)
#pragma unroll
            for (int ni = 0; ni < 4; ni++) {
                int col = wc + ni * 16 + l15;
#pragma unroll
                for (int r = 0; r < 4; r++)
                    Ct[wr + mi * 16 + quad * 4 + r][col] = f2bf(acc1[mi][ni][r]);
            }
        __syncthreads();
#pragma unroll
        for (int it = 0; it < 8; it++) {
            int c = it * 256 + tid;
            int o = c >> 3, j = c & 7;
            int hh = o >> 7, mr = o & 127;
            int m = m0 + mr, b = m >> 11, si = m & (SS - 1);
            uint4 v = *reinterpret_cast<const uint4*>(&Ct[mr][hh * 64 + j * 8]);
            *reinterpret_cast<uint4*>(
                &qh[((size_t)((b * NHEADS + h0 + hh) * SS + si)) * DHEAD + j * 8]) = v;
        }
        // pass 2: V1 -> heads-layout v1h
        __syncthreads();
#pragma unroll
        for (int mi = 0; mi < 4; mi++)
#pragma unroll
            for (int ni = 0; ni < 4; ni++) {
                int col = wc + ni * 16 + l15;
#pragma unroll
                for (int r = 0; r < 4; r++)
                    Ct[wr + mi * 16 + quad * 4 + r][col] = f2bf(acc2[mi][ni][r]);
            }
        __syncthreads();
#pragma unroll
        for (int it = 0; it < 8; it++) {
            int c = it * 256 + tid;
            int o = c >> 3, j = c & 7;
            int hh = o >> 7, mr = o & 127;
            int m = m0 + mr, b = m >> 11, si = m & (SS - 1);
            uint4 v = *reinterpret_cast<const uint4*>(&Ct[mr][hh * 64 + j * 8]);
            *reinterpret_cast<uint4*>(
                &v1h[((size_t)((b * NHEADS + h0 + hh) * SS + si)) * DHEAD + j * 8]) = v;
        }
    } else {
        // V -> pre-transposed swizzled V^T tiles
        __syncthreads();
#pragma unroll
        for (int mi = 0; mi < 4; mi++)
#pragma unroll
            for (int ni = 0; ni < 4; ni++) {
                int col = wc + ni * 16 + l15;
#pragma unroll
                for (int r = 0; r < 4; r++)
                    Ct[wr + mi * 16 + quad * 4 + r][col] = f2bf(acc1[mi][ni][r]);
            }
        __syncthreads();
        int b = m0 >> 11;
        int s0 = m0 & (SS - 1);
#pragma unroll
        for (int it = 0; it < 8; it++) {
            int c = it * 256 + tid;
            int dh  = c & 63;
            int k16 = (c >> 6) & 15;
            int hh  = c >> 10;
            short8 v;
#pragma unroll
            for (int e = 0; e < 8; e++)
                v[e] = (short)Ct[k16 * 8 + e][hh * 64 + dh];
            int kt = (s0 >> 6) + (k16 >> 3);
            size_t off = ((size_t)((b * NHEADS + h0 + hh) * 32 + kt)) * 4096
                       + dh * 64 + (((k16 & 7) ^ (dh & 7)) << 3);
            *reinterpret_cast<short8*>(&vt[off]) = v;
        }
    }
}

// ---------------- flash attention: causal-paired 8-wave blocks, 2-tile unrolled pipeline.
// 4-slot K/V ring buffer; ONE barrier per TWO tiles (best measured config, r8). ----
template<bool MASKED>
static __device__ __forceinline__ void attn_tile(
        const ushort_t* __restrict__ Kc, const ushort_t* __restrict__ Vc, int kbase,
        int quad, int l15, int q0w, const short8* qf, const short8& onesf,
        ushort_t* __restrict__ Psw, float4v* Oa, float4v& sum4) {
    float4v sa[4];
#pragma unroll
    for (int t2 = 0; t2 < 4; t2++) sa[t2] = (float4v){0.f, 0.f, 0.f, 0.f};
    __builtin_amdgcn_s_setprio(1);
#pragma unroll
    for (int t2 = 0; t2 < 4; t2++) {
        int key = t2 * 16 + l15;
        int ro = key * 64, sw = key & 7;
#pragma unroll
        for (int half = 0; half < 2; half++) {
            short8 kf = *reinterpret_cast<const short8*>(&Kc[ro + (((half * 4 + quad) ^ sw) << 3)]);
            sa[t2] = __builtin_amdgcn_mfma_f32_16x16x32_bf16(kf, qf[half], sa[t2], 0, 0, 0);
        }
    }
    __builtin_amdgcn_s_setprio(0);
    int query = q0w + l15;
    int swl = l15 & 7;
#pragma unroll
    for (int t2 = 0; t2 < 4; t2++) {
        float p[4];
#pragma unroll
        for (int r = 0; r < 4; r++) {
            float e = ex2(sa[t2][r]);          // 2^(scaled score): scale folded into Q
            if (MASKED) {
                int key = kbase + t2 * 16 + quad * 4 + r;
                p[r] = (key <= query) ? e : 0.f;
            } else {
                p[r] = e;
            }
        }
        unsigned w0 = cvtpk_bf16(p[0], p[1]);
        unsigned w1 = cvtpk_bf16(p[2], p[3]);
        int chunk = (((t2 * 2 + (quad >> 1)) ^ swl) << 3) + (quad & 1) * 4;
        *reinterpret_cast<unsigned*>(&Psw[l15 * 64 + chunk])     = w0;
        *reinterpret_cast<unsigned*>(&Psw[l15 * 64 + chunk + 2]) = w1;
    }
    // per-wave LDS: compiler-inserted lgkmcnt orders writes before these reads
    short8 pf0 = *reinterpret_cast<const short8*>(&Psw[l15 * 64 + ((quad ^ swl) << 3)]);
    short8 pf1 = *reinterpret_cast<const short8*>(&Psw[l15 * 64 + (((4 + quad) ^ swl) << 3)]);
    __builtin_amdgcn_s_setprio(1);
#pragma unroll
    for (int t = 0; t < 4; t++) {
        int dh = t * 16 + l15;
        int ro = dh * 64, sw = dh & 7;
        short8 vf0 = *reinterpret_cast<const short8*>(&Vc[ro + ((quad ^ sw) << 3)]);
        short8 vf1 = *reinterpret_cast<const short8*>(&Vc[ro + (((4 + quad) ^ sw) << 3)]);
        Oa[t] = __builtin_amdgcn_mfma_f32_16x16x32_bf16(pf0, vf0, Oa[t], 0, 0, 0);
        Oa[t] = __builtin_amdgcn_mfma_f32_16x16x32_bf16(pf1, vf1, Oa[t], 0, 0, 0);
    }
    // softmax denominator on the matrix pipe: sum4[r] = sum_k P[query(quad*4+r)][k]
    sum4 = __builtin_amdgcn_mfma_f32_16x16x32_bf16(pf0, onesf, sum4, 0, 0, 0);
    sum4 = __builtin_amdgcn_mfma_f32_16x16x32_bf16(pf1, onesf, sum4, 0, 0, 0);
    __builtin_amdgcn_s_setprio(0);
}

__global__ __launch_bounds__(512, 4) void attn_kernel(
        const ushort_t* __restrict__ qh, const float* __restrict__ kf32,
        const ushort_t* __restrict__ khb, const ushort_t* __restrict__ vtb,
        const ushort_t* __restrict__ v1h, float* __restrict__ out) {
    __shared__ __align__(16) ushort_t Ks[4][4096];   // [key][dh] swizzled, 4-slot ring
    __shared__ __align__(16) ushort_t Vt[4][4096];   // [dh][key] swizzled, 4-slot ring
    __shared__ __align__(16) ushort_t Ps[8][1024];   // per-wave swizzled P; 80KB LDS total

    // 512 blocks: 16 pairs x 32 bh; longest pair (p=0) first, 4 heads per XCD
    int bid = blockIdx.x;
    int bh = (bid & 7) * 4 + ((bid >> 3) & 3);
    int p  = bid >> 5;                    // 0..15

    int tid = threadIdx.x, wave = tid >> 6, lane = tid & 63, quad = lane >> 4, l15 = lane & 15;
    int jq  = (wave < 4) ? p : (31 - p);  // this wave's 64-query block
    int q0w = jq * 64 + (wave & 3) * 16;
    const ushort_t* qp  = qh  + (size_t)bh * SS * DHEAD;
    const float*    kp  = kf32 + (size_t)bh * SS * DHEAD;
    const ushort_t* v1p = v1h + (size_t)bh * SS * DHEAD;
    const ushort_t* ktb = khb + (size_t)bh * 32 * 4096;
    const ushort_t* vtt = vtb + (size_t)bh * 32 * 4096;

    short8 qf[2];
    qf[0] = *reinterpret_cast<const short8*>(&qp[(q0w + l15) * DHEAD + quad * 8]);
    qf[1] = *reinterpret_cast<const short8*>(&qp[(q0w + l15) * DHEAD + 32 + quad * 8]);
    short8 onesf;
#pragma unroll
    for (int j = 0; j < 8; j++) onesf[j] = (short)0x3F80;   // bf16 1.0

    float4v Oa[4];
#pragma unroll
    for (int t = 0; t < 4; t++) Oa[t] = (float4v){0.f, 0.f, 0.f, 0.f};
    float4v sum4 = (float4v){0.f, 0.f, 0.f, 0.f};

    int gi = tid * 8;            // 512 threads x 16B = one full 8KB tile per buffer
    int li = (tid & 448) * 8;    // wave-uniform LDS base

    int ntiles = 32 - p;         // >= 17 always; HI block's range covers LO's
    // prologue: stage tiles 0 and 1
    gload16(ktb + gi, &Ks[0][li]);               gload16(vtt + gi, &Vt[0][li]);
    gload16(ktb + 4096 + gi, &Ks[1][li]);        gload16(vtt + 4096 + gi, &Vt[1][li]);

    int kt = 0;
    for (; kt + 1 < ntiles; kt += 2) {
        __syncthreads();   // drains vmcnt -> slots kt&3,(kt+1)&3 ready; old reads done
        if (kt + 2 < ntiles) {
            const ushort_t* gk = ktb + (size_t)(kt + 2) * 4096;
            const ushort_t* gv = vtt + (size_t)(kt + 2) * 4096;
            int nb = (kt + 2) & 3;
            gload16(gk + gi, &Ks[nb][li]);
            gload16(gv + gi, &Vt[nb][li]);
        }
        if (kt + 3 < ntiles) {
            const ushort_t* gk = ktb + (size_t)(kt + 3) * 4096;
            const ushort_t* gv = vtt + (size_t)(kt + 3) * 4096;
            int nb = (kt + 3) & 3;
            gload16(gk + gi, &Ks[nb][li]);
            gload16(gv + gi, &Vt[nb][li]);
        }
        // tile kt
        {
            int kbase = kt * 64, sl = kt & 3;
            if (kbase <= q0w + 15) {
                if (kbase + 63 <= q0w)
                    attn_tile<false>(Ks[sl], Vt[sl], kbase, quad, l15, q0w, qf, onesf,
                                     &Ps[wave][0], Oa, sum4);
                else
                    attn_tile<true>(Ks[sl], Vt[sl], kbase, quad, l15, q0w, qf, onesf,
                                    &Ps[wave][0], Oa, sum4);
            }
        }
        // tile kt+1
        {
            int kbase = (kt + 1) * 64, sl = (kt + 1) & 3;
            if (kbase <= q0w + 15) {
                if (kbase + 63 <= q0w)
                    attn_tile<false>(Ks[sl], Vt[sl], kbase, quad, l15, q0w, qf, onesf,
                                     &Ps[wave][0], Oa, sum4);
                else
                    attn_tile<true>(Ks[sl], Vt[sl], kbase, quad, l15, q0w, qf, onesf,
                                    &Ps[wave][0], Oa, sum4);
            }
        }
    }
    if (kt < ntiles) {           // odd tail: one last tile, already staged
        __syncthreads();
        int kbase = kt * 64, sl = kt & 3;
        if (kbase <= q0w + 15) {
            if (kbase + 63 <= q0w)
                attn_tile<false>(Ks[sl], Vt[sl], kbase, quad, l15, q0w, qf, onesf,
                                 &Ps[wave][0], Oa, sum4);
            else
                attn_tile<true>(Ks[sl], Vt[sl], kbase, quad, l15, q0w, qf, onesf,
                                &Ps[wave][0], Oa, sum4);
        }
    }

    // Ps[wave] is dead now: alias per-wave sdiag (16 f32) onto it
    float* sdiag = reinterpret_cast<float*>(&Ps[wave][32]);

    // diagonal extra key: s_d = qs[i] . rope(k_roped[i]) (log2 domain), value v1[i]
    {
        int sk = q0w + l15;
        const float* krow = kp + (size_t)sk * DHEAD;
        short8 k1lo, k1hi;
#pragma unroll
        for (int j = 0; j < 8; j++) {
            int d = quad * 8 + j;
            float f = __expf(-(float)d * LN1E4_D32);
            float th = (float)sk * f;
            float cv, sv;
            __sincosf(th, &sv, &cv);
            float a = krow[d], b2 = krow[d + 32];
            k1lo[j] = (short)f2bf(a * cv - b2 * sv);
            k1hi[j] = (short)f2bf(b2 * cv + a * sv);
        }
        float4v sd4 = (float4v){0.f, 0.f, 0.f, 0.f};
        sd4 = __builtin_amdgcn_mfma_f32_16x16x32_bf16(qf[0], k1lo, sd4, 0, 0, 0);
        sd4 = __builtin_amdgcn_mfma_f32_16x16x32_bf16(qf[1], k1hi, sd4, 0, 0, 0);
#pragma unroll
        for (int r = 0; r < 4; r++)
            if (l15 == quad * 4 + r) sdiag[l15] = sd4[r];
        // per-wave LDS write->read ordered by lgkmcnt within the wave; no barrier needed

        int b = bh >> 4, h = bh & (NHEADS - 1);
#pragma unroll
        for (int r = 0; r < 4; r++) {
            float pd = ex2(sdiag[quad * 4 + r]);
            int query = q0w + quad * 4 + r;
            float linv = 1.f / (sum4[r] + pd);
#pragma unroll
            for (int t = 0; t < 4; t++) {
                float v1v = bf2f(v1p[query * DHEAD + t * 16 + l15]);
                float o = (Oa[t][r] + pd * v1v) * linv;
                out[(b * SS + query) * DM + h * DHEAD + t * 16 + l15] = o;
            }
        }
    }
}

extern "C" void kernel_launch(void* const* d_in, const int* in_sizes, int n_in,
                              void* d_out, int out_size, void* d_ws, size_t ws_size,
                              hipStream_t stream) {
    const float* x  = (const float*)d_in[0];
    const float* y  = (const float*)d_in[1];
    const float* wq = (const float*)d_in[2];
    // d_in[3] = wk is unused by the reference
    const float* wv = (const float*)d_in[4];
    const float* wo = (const float*)d_in[5];
    float* outp  = (float*)d_out;                       // output 0: (2,2048,1024) f32
    float* k_out = outp + (size_t)BB * SS * DM;         // output 1: roped K (2,16,2048,64) f32

    char* ws = (char*)d_ws;
    ushort_t* vtb = (ushort_t*)(ws);                  // 8 MB  V^T swizzled attn tiles
    ushort_t* v1b = (ushort_t*)(ws + (8ull  << 20));  // 8 MB  V1 heads-layout bf16
    ushort_t* qhb = (ushort_t*)(ws + (16ull << 20));  // 8 MB  Q heads-layout bf16 (pre-scaled)
    ushort_t* khb = (ushort_t*)(ws + (24ull << 20));  // 8 MB  roped-K swizzled attn tiles
    ushort_t* xb  = (ushort_t*)(ws + (32ull << 20));  // 8 MB  x bf16 GEMM tiles
    ushort_t* yb  = (ushort_t*)(ws + (40ull << 20));  // 8 MB  y bf16 GEMM tiles
    ushort_t* wqb = (ushort_t*)(ws + (48ull << 20));  // 2 MB
    ushort_t* wvb = (ushort_t*)(ws + (50ull << 20));  // 2 MB
    ushort_t* wob = (ushort_t*)(ws + (52ull << 20));  // 2 MB  (total 54 MB)

    prep_kernel<<<4608, 256, 0, stream>>>(x, y, wq, wv, wo, xb, wqb, wvb, wob,
                                          k_out, khb, yb);
    gemm3_kernel<<<512, 256, 0, stream>>>(xb, yb, wqb, wvb, wob, qhb, vtb, v1b);
    attn_kernel<<<512, 512, 0, stream>>>(qhb, k_out, khb, vtb, v1b, outp);
}